// Round 1
// baseline (557.811 us; speedup 1.0000x reference)
//
#include <hip/hip_runtime.h>
#include <hip/hip_bf16.h>
#include <stdint.h>

#define NB 32
#define NS 4096
#define ND 512

typedef __attribute__((ext_vector_type(8))) short short8;
typedef __attribute__((ext_vector_type(4))) short short4v;
typedef __attribute__((ext_vector_type(4))) float floatx4;

__device__ __forceinline__ short f2bf(float f) {
    unsigned int u = __builtin_bit_cast(unsigned int, f);
    return (short)((u + 0x8000u) >> 16);
}

__device__ __forceinline__ float fast_tanh(float x) {
    float e = __expf(2.0f * x);
    return 1.0f - 2.0f * __builtin_amdgcn_rcpf(e + 1.0f);
}

// K1a: qb[b][e] = sum_k query[b][k] * W1[k][e] + b1[e] + b2[e]
__global__ void __launch_bounds__(256) qproj_kernel(
    const float* __restrict__ query, const float* __restrict__ W1,
    const float* __restrict__ b1, const float* __restrict__ b2,
    float* __restrict__ qb) {
    int b = blockIdx.x;
    int t = threadIdx.x;
    __shared__ float q[ND];
    q[t] = query[b * ND + t];
    q[t + 256] = query[b * ND + t + 256];
    __syncthreads();
    float acc0 = 0.f, acc1 = 0.f;
#pragma unroll 8
    for (int k = 0; k < ND; k++) {
        float qk = q[k];
        acc0 += qk * W1[k * ND + t];
        acc1 += qk * W1[k * ND + t + 256];
    }
    qb[b * ND + t] = acc0 + b1[t] + b2[t];
    qb[b * ND + t + 256] = acc1 + b1[t + 256] + b2[t + 256];
}

// K1b: W2T[n][k] = bf16(W2[k][n])   (512x512)
__global__ void __launch_bounds__(256) w2t_kernel(
    const float* __restrict__ W2, unsigned short* __restrict__ W2T) {
    int t = blockIdx.x * 256 + threadIdx.x;   // 32768 threads
    int n = t & 511;
    int kb = t >> 9;                          // 0..63, covers 8 k each
    short8 v;
#pragma unroll
    for (int j = 0; j < 8; j++)
        v[j] = f2bf(W2[(size_t)(kb * 8 + j) * ND + n]);
    *(short8*)&W2T[(size_t)n * ND + kb * 8] = v;
}

// K2: scores[b][s] += sum_{e in ntile} tanh( (values[b] @ W2)[s][e] + qb[b][e] ) * V[e]
__global__ void __launch_bounds__(256) scores_kernel(
    const float* __restrict__ values, const unsigned short* __restrict__ W2T,
    const float* __restrict__ qb, const float* __restrict__ V,
    float* __restrict__ scores) {
    const int nt = blockIdx.x;   // 0..3
    const int st = blockIdx.y;   // 0..31
    const int b  = blockIdx.z;   // 0..31
    const int n0 = nt * 128, s0 = st * 128;

    __shared__ __align__(16) unsigned short sA[128 * 32]; // [row][k] bf16, 64B/row
    __shared__ __align__(16) unsigned short sB[128 * 32]; // [n][k]  bf16, 64B/row
    __shared__ float sQb[128];
    __shared__ float sV[128];

    const int tid  = threadIdx.x;
    const int lane = tid & 63;
    const int wave = tid >> 6;          // 0..3
    const int wr = wave >> 1, wc = wave & 1;

    if (tid < 128) {
        sQb[tid] = qb[b * ND + n0 + tid];
        sV[tid]  = V[n0 + tid];
    }

    floatx4 acc[4][4] = {};

    // A staging mapping: thread -> (row, h); loads float4 at k = h*4 + 8j (32B pair segments)
    const int arow = tid >> 1, ah = tid & 1;
    const float* arow_ptr = values + ((size_t)b * NS + s0 + arow) * ND;

    const int mr  = lane & 15;
    const int kq8 = (lane >> 4) * 8;
    const unsigned short* aBase = &sA[(wr * 64 + mr) * 32 + kq8];
    const unsigned short* bBase = &sB[(wc * 64 + mr) * 32 + kq8];

    for (int k0 = 0; k0 < ND; k0 += 32) {
        // ---- stage B via async global->LDS (16B per lane-op) ----
#pragma unroll
        for (int r = 0; r < 2; r++) {
            int c = tid + r * 256;           // 512 chunks of 16B
            int n = c >> 2, kq = c & 3;
            const unsigned short* src = W2T + (size_t)(n0 + n) * ND + k0 + kq * 8;
            __builtin_amdgcn_global_load_lds(
                (const __attribute__((address_space(1))) unsigned int*)src,
                (__attribute__((address_space(3))) unsigned int*)&sB[c * 8],
                16, 0, 0);
        }
        // ---- stage A: fp32 load + convert + ds_write ----
        const float4* ap = (const float4*)(arow_ptr + k0);
#pragma unroll
        for (int j = 0; j < 4; j++) {
            float4 a = ap[ah + 2 * j];       // elements k0 + ah*4 + 8j .. +4
            short4v w;
            w[0] = f2bf(a.x); w[1] = f2bf(a.y); w[2] = f2bf(a.z); w[3] = f2bf(a.w);
            *(short4v*)&sA[arow * 32 + ah * 4 + j * 8] = w;
        }
        __syncthreads();

        short8 af[4], bfr[4];
#pragma unroll
        for (int i = 0; i < 4; i++) af[i]  = *(const short8*)(aBase + i * 16 * 32);
#pragma unroll
        for (int j = 0; j < 4; j++) bfr[j] = *(const short8*)(bBase + j * 16 * 32);
#pragma unroll
        for (int i = 0; i < 4; i++)
#pragma unroll
            for (int j = 0; j < 4; j++)
                acc[i][j] = __builtin_amdgcn_mfma_f32_16x16x32_bf16(af[i], bfr[j], acc[i][j], 0, 0, 0);
        __syncthreads();
    }

    // ---- epilogue: tanh(P + qb) * V, reduce over cols, atomic partial scores ----
    const int colb = wc * 64 + mr;           // + j*16
    const int rowq = lane >> 4;              // row = wr*64 + i*16 + rowq*4 + r
    float vcoef[4], qadd[4];
#pragma unroll
    for (int j = 0; j < 4; j++) { vcoef[j] = sV[colb + j * 16]; qadd[j] = sQb[colb + j * 16]; }

#pragma unroll
    for (int i = 0; i < 4; i++) {
#pragma unroll
        for (int r = 0; r < 4; r++) {
            float p = 0.f;
#pragma unroll
            for (int j = 0; j < 4; j++)
                p += fast_tanh(acc[i][j][r] + qadd[j]) * vcoef[j];
            p += __shfl_xor(p, 1);
            p += __shfl_xor(p, 2);
            p += __shfl_xor(p, 4);
            p += __shfl_xor(p, 8);
            if (mr == 0) {
                int row = wr * 64 + i * 16 + rowq * 4 + r;
                atomicAdd(&scores[(size_t)b * NS + s0 + row], p);
            }
        }
    }
}

// K3: softmax over S per batch
__global__ void __launch_bounds__(256) softmax_kernel(
    const float* __restrict__ scores, float* __restrict__ attn) {
    int b = blockIdx.x;
    int t = threadIdx.x;
    __shared__ float red[4];
    __shared__ float bcast[2];
    const float* sc = scores + (size_t)b * NS;
    float v[16];
    float m = -1e30f;
#pragma unroll
    for (int i = 0; i < 16; i++) { v[i] = sc[t + i * 256]; m = fmaxf(m, v[i]); }
    for (int o = 32; o; o >>= 1) m = fmaxf(m, __shfl_xor(m, o));
    if ((t & 63) == 0) red[t >> 6] = m;
    __syncthreads();
    if (t == 0) bcast[0] = fmaxf(fmaxf(red[0], red[1]), fmaxf(red[2], red[3]));
    __syncthreads();
    m = bcast[0];
    float sum = 0.f;
#pragma unroll
    for (int i = 0; i < 16; i++) { v[i] = __expf(v[i] - m); sum += v[i]; }
    for (int o = 32; o; o >>= 1) sum += __shfl_xor(sum, o);
    if ((t & 63) == 0) red[t >> 6] = sum;
    __syncthreads();
    if (t == 0) bcast[1] = red[0] + red[1] + red[2] + red[3];
    __syncthreads();
    float inv = 1.0f / bcast[1];
    float* ao = attn + (size_t)b * NS;
#pragma unroll
    for (int i = 0; i < 16; i++) ao[t + i * 256] = v[i] * inv;
}

// K4: ctx[b][d] = sum_s attn[b][s] * values[b][s][d]   (atomic partials over s-chunks)
__global__ void __launch_bounds__(256) context_kernel(
    const float* __restrict__ values, const float* __restrict__ attn,
    float* __restrict__ ctx) {
    int sc = blockIdx.x;  // 0..31 (128 s each)
    int b  = blockIdx.y;  // 0..31
    int t  = threadIdx.x;
    __shared__ float sAttn[128];
    if (t < 128) sAttn[t] = attn[(size_t)b * NS + sc * 128 + t];
    __syncthreads();
    int d = t * 2;
    const float2* vp = (const float2*)(values + ((size_t)b * NS + sc * 128) * ND + d);
    float ax = 0.f, ay = 0.f;
#pragma unroll 8
    for (int s = 0; s < 128; s++) {
        float a = sAttn[s];
        float2 v = vp[(size_t)s * 256];
        ax += a * v.x; ay += a * v.y;
    }
    atomicAdd(&ctx[b * ND + d], ax);
    atomicAdd(&ctx[b * ND + d + 1], ay);
}

extern "C" void kernel_launch(void* const* d_in, const int* in_sizes, int n_in,
                              void* d_out, int out_size, void* d_ws, size_t ws_size,
                              hipStream_t stream) {
    const float* query  = (const float*)d_in[0];
    const float* values = (const float*)d_in[1];
    const float* W1     = (const float*)d_in[2];
    const float* b1     = (const float*)d_in[3];
    const float* W2     = (const float*)d_in[4];
    const float* b2     = (const float*)d_in[5];
    const float* V      = (const float*)d_in[6];
    // d_in[7] = bv: uniform shift over softmax axis -> no effect on outputs. Dropped.

    float* ctx_out  = (float*)d_out;               // [32,512]
    float* attn_out = (float*)d_out + NB * ND;     // [32,4096]

    char* ws = (char*)d_ws;
    float*          qb     = (float*)ws;                              // 64 KB
    unsigned short* W2T    = (unsigned short*)(ws + 64 * 1024);       // 512 KB
    float*          scores = (float*)(ws + 64 * 1024 + 512 * 1024);   // 512 KB

    hipMemsetAsync(scores, 0, (size_t)NB * NS * sizeof(float), stream);
    hipMemsetAsync(ctx_out, 0, (size_t)NB * ND * sizeof(float), stream);

    qproj_kernel<<<NB, 256, 0, stream>>>(query, W1, b1, b2, qb);
    w2t_kernel<<<128, 256, 0, stream>>>(W2, W2T);
    scores_kernel<<<dim3(4, 32, 32), 256, 0, stream>>>(values, W2T, qb, V, scores);
    softmax_kernel<<<NB, 256, 0, stream>>>(scores, attn_out);
    context_kernel<<<dim3(32, 32), 256, 0, stream>>>(values, attn_out, ctx_out);
}

// Round 2
// 535.046 us; speedup vs baseline: 1.0425x; 1.0425x over previous
//
#include <hip/hip_runtime.h>
#include <hip/hip_bf16.h>
#include <stdint.h>

#define NB 32
#define NS 4096
#define ND 512

typedef __attribute__((ext_vector_type(8))) short short8;
typedef __attribute__((ext_vector_type(4))) float floatx4;

__device__ __forceinline__ short f2bf(float f) {
    unsigned int u = __builtin_bit_cast(unsigned int, f);
    return (short)((u + 0x8000u) >> 16);
}

__device__ __forceinline__ float fast_tanh(float x) {
    float e = __expf(2.0f * x);
    return 1.0f - 2.0f * __builtin_amdgcn_rcpf(e + 1.0f);
}

__device__ __forceinline__ short8 pack8(float4 a, float4 b) {
    short8 w;
    w[0] = f2bf(a.x); w[1] = f2bf(a.y); w[2] = f2bf(a.z); w[3] = f2bf(a.w);
    w[4] = f2bf(b.x); w[5] = f2bf(b.y); w[6] = f2bf(b.z); w[7] = f2bf(b.w);
    return w;
}

// K1a: qb[b][e] = sum_k query[b][k] * W1[k][e] + b1[e] + b2[e]
__global__ void __launch_bounds__(256) qproj_kernel(
    const float* __restrict__ query, const float* __restrict__ W1,
    const float* __restrict__ b1, const float* __restrict__ b2,
    float* __restrict__ qb) {
    int b = blockIdx.x;
    int t = threadIdx.x;
    __shared__ float q[ND];
    q[t] = query[b * ND + t];
    q[t + 256] = query[b * ND + t + 256];
    __syncthreads();
    float acc0 = 0.f, acc1 = 0.f;
#pragma unroll 8
    for (int k = 0; k < ND; k++) {
        float qk = q[k];
        acc0 += qk * W1[k * ND + t];
        acc1 += qk * W1[k * ND + t + 256];
    }
    qb[b * ND + t] = acc0 + b1[t] + b2[t];
    qb[b * ND + t + 256] = acc1 + b1[t + 256] + b2[t + 256];
}

// K1b: shuffle W2 (fp32 [k][e]) into bf16 tiled layout for global_load_lds:
// W2Tt chunk g encodes (nt: g>>14, ks: (g>>10)&15, kq: (g>>8)&3, n: g&255);
// chunk holds bf16(W2[ks*32+kq*8+j][nt*256+n]) for j=0..7, at W2Tt + g*8.
__global__ void __launch_bounds__(256) w2t_kernel(
    const float* __restrict__ W2, unsigned short* __restrict__ W2Tt) {
    int g = blockIdx.x * 256 + threadIdx.x;   // 32768 chunks
    int nt = g >> 14;
    int ks = (g >> 10) & 15;
    int kq = (g >> 8) & 3;
    int n  = g & 255;
    int e  = nt * 256 + n;
    int k0 = ks * 32 + kq * 8;
    short8 v;
#pragma unroll
    for (int j = 0; j < 8; j++)
        v[j] = f2bf(W2[(size_t)(k0 + j) * ND + e]);
    *(short8*)&W2Tt[(size_t)g * 8] = v;
}

// K2: scores[b][s] += sum_{e in 256-wide ntile} tanh((values[b] @ W2)[s][e] + qb[b][e]) * V[e]
// Block tile: 128 rows (s) x 256 cols (e), K=512 in 16 steps of 32.
// LDS layout (kq-major 16B chunks): A chunk = kq*128 + row; B chunk = kq*256 + n.
__global__ void __launch_bounds__(256, 2) scores_kernel(
    const float* __restrict__ values, const unsigned short* __restrict__ W2Tt,
    const float* __restrict__ qb, const float* __restrict__ V,
    float* __restrict__ scores) {
    const int nt = blockIdx.x;   // 0..1  (n-width 256)
    const int st = blockIdx.y;   // 0..31
    const int b  = blockIdx.z;   // 0..31
    const int n0 = nt * 256, s0 = st * 128;

    __shared__ __align__(16) unsigned short sA[2][4096];   // 2 x 8 KB
    __shared__ __align__(16) unsigned short sB[2][8192];   // 2 x 16 KB
    __shared__ float sQb[256];
    __shared__ float sV[256];

    const int tid  = threadIdx.x;
    const int lane = tid & 63;
    const int wave = tid >> 6;          // 0..3
    const int wr = wave >> 1, wc = wave & 1;
    const int mr = lane & 15;
    const int q  = lane >> 4;

    sQb[tid] = qb[b * ND + n0 + tid];
    sV[tid]  = V[n0 + tid];

    floatx4 acc[4][8] = {};

    // A staging: thread -> (row = tid>>1, h = tid&1); covers floats k0 + h*16 .. +16
    const int arow = tid >> 1, ah = tid & 1;
    const float* arow_ptr = values + ((size_t)b * NS + s0 + arow) * ND + ah * 16;
    const int awr0 = (2 * ah * 128 + arow) * 8;          // kq=2h chunk
    const int awr1 = ((2 * ah + 1) * 128 + arow) * 8;    // kq=2h+1 chunk

    // B staging source base (contiguous 8 KB per k-step)
    const unsigned short* bsrc0 = W2Tt + (size_t)(nt * 16) * 8192;

    // fragment read bases (offsets in shorts)
    const int aoff = (q * 128 + wr * 64 + mr) * 8;       // + i*128
    const int boff = (q * 256 + wc * 128 + mr) * 8;      // + j*128

    // ---- prologue: stage k-step 0 into buffer 0 ----
    {
#pragma unroll
        for (int r = 0; r < 4; r++) {
            int c = tid + 256 * r;
            __builtin_amdgcn_global_load_lds(
                (const __attribute__((address_space(1))) unsigned int*)(bsrc0 + c * 8),
                (__attribute__((address_space(3))) unsigned int*)&sB[0][c * 8],
                16, 0, 0);
        }
        const float4* ap = (const float4*)arow_ptr;
        float4 x0 = ap[0], x1 = ap[1], x2 = ap[2], x3 = ap[3];
        *(short8*)&sA[0][awr0] = pack8(x0, x1);
        *(short8*)&sA[0][awr1] = pack8(x2, x3);
    }
    __syncthreads();

    for (int ks = 0; ks < 16; ks++) {
        const int cur = ks & 1, nxt = cur ^ 1;
        float4 x0, x1, x2, x3;
        if (ks < 15) {
            // prefetch B[ks+1] via async global->LDS
            const unsigned short* bsrc = bsrc0 + (size_t)(ks + 1) * 8192;
#pragma unroll
            for (int r = 0; r < 4; r++) {
                int c = tid + 256 * r;
                __builtin_amdgcn_global_load_lds(
                    (const __attribute__((address_space(1))) unsigned int*)(bsrc + c * 8),
                    (__attribute__((address_space(3))) unsigned int*)&sB[nxt][c * 8],
                    16, 0, 0);
            }
            // prefetch A[ks+1] into registers
            const float4* ap = (const float4*)(arow_ptr + (ks + 1) * 32);
            x0 = ap[0]; x1 = ap[1]; x2 = ap[2]; x3 = ap[3];
        }

        short8 af[4], bfr[8];
#pragma unroll
        for (int i = 0; i < 4; i++) af[i]  = *(const short8*)&sA[cur][aoff + i * 128];
#pragma unroll
        for (int j = 0; j < 8; j++) bfr[j] = *(const short8*)&sB[cur][boff + j * 128];
#pragma unroll
        for (int i = 0; i < 4; i++)
#pragma unroll
            for (int j = 0; j < 8; j++)
                acc[i][j] = __builtin_amdgcn_mfma_f32_16x16x32_bf16(af[i], bfr[j], acc[i][j], 0, 0, 0);

        if (ks < 15) {
            *(short8*)&sA[nxt][awr0] = pack8(x0, x1);
            *(short8*)&sA[nxt][awr1] = pack8(x2, x3);
        }
        __syncthreads();
    }

    // ---- epilogue: tanh(P + qb) * V, reduce over cols, atomic partial scores ----
    float vcoef[8], qadd[8];
#pragma unroll
    for (int j = 0; j < 8; j++) {
        int col = wc * 128 + j * 16 + mr;
        vcoef[j] = sV[col];
        qadd[j]  = sQb[col];
    }

#pragma unroll
    for (int i = 0; i < 4; i++) {
#pragma unroll
        for (int r = 0; r < 4; r++) {
            float p = 0.f;
#pragma unroll
            for (int j = 0; j < 8; j++)
                p += fast_tanh(acc[i][j][r] + qadd[j]) * vcoef[j];
            p += __shfl_xor(p, 1);
            p += __shfl_xor(p, 2);
            p += __shfl_xor(p, 4);
            p += __shfl_xor(p, 8);
            if (mr == 0) {
                int row = wr * 64 + i * 16 + q * 4 + r;
                atomicAdd(&scores[(size_t)b * NS + s0 + row], p);
            }
        }
    }
}

// K3: softmax over S per batch
__global__ void __launch_bounds__(256) softmax_kernel(
    const float* __restrict__ scores, float* __restrict__ attn) {
    int b = blockIdx.x;
    int t = threadIdx.x;
    __shared__ float red[4];
    __shared__ float bcast[2];
    const float* sc = scores + (size_t)b * NS;
    float v[16];
    float m = -1e30f;
#pragma unroll
    for (int i = 0; i < 16; i++) { v[i] = sc[t + i * 256]; m = fmaxf(m, v[i]); }
    for (int o = 32; o; o >>= 1) m = fmaxf(m, __shfl_xor(m, o));
    if ((t & 63) == 0) red[t >> 6] = m;
    __syncthreads();
    if (t == 0) bcast[0] = fmaxf(fmaxf(red[0], red[1]), fmaxf(red[2], red[3]));
    __syncthreads();
    m = bcast[0];
    float sum = 0.f;
#pragma unroll
    for (int i = 0; i < 16; i++) { v[i] = __expf(v[i] - m); sum += v[i]; }
    for (int o = 32; o; o >>= 1) sum += __shfl_xor(sum, o);
    if ((t & 63) == 0) red[t >> 6] = sum;
    __syncthreads();
    if (t == 0) bcast[1] = red[0] + red[1] + red[2] + red[3];
    __syncthreads();
    float inv = 1.0f / bcast[1];
    float* ao = attn + (size_t)b * NS;
#pragma unroll
    for (int i = 0; i < 16; i++) ao[t + i * 256] = v[i] * inv;
}

// K4a: pctx[sc][b][d] = sum_{s in chunk} attn[b][s] * values[b][s][d]  (no atomics)
__global__ void __launch_bounds__(256) context_partial_kernel(
    const float* __restrict__ values, const float* __restrict__ attn,
    float* __restrict__ pctx) {
    int sc = blockIdx.x;  // 0..7 (512 s each)
    int b  = blockIdx.y;  // 0..31
    int t  = threadIdx.x;
    __shared__ float sAttn[512];
    sAttn[t]       = attn[(size_t)b * NS + sc * 512 + t];
    sAttn[t + 256] = attn[(size_t)b * NS + sc * 512 + t + 256];
    __syncthreads();
    int d = t * 2;
    const float2* vp = (const float2*)(values + ((size_t)b * NS + sc * 512) * ND + d);
    float ax = 0.f, ay = 0.f;
#pragma unroll 8
    for (int s = 0; s < 512; s++) {
        float a = sAttn[s];
        float2 v = vp[(size_t)s * 256];
        ax += a * v.x; ay += a * v.y;
    }
    pctx[((size_t)sc * 32 + b) * ND + d]     = ax;
    pctx[((size_t)sc * 32 + b) * ND + d + 1] = ay;
}

// K4b: ctx[b][d] = sum_sc pctx[sc][b][d]
__global__ void __launch_bounds__(256) context_reduce_kernel(
    const float* __restrict__ pctx, float* __restrict__ ctx) {
    int i = blockIdx.x * 256 + threadIdx.x;  // 16384
    float s = 0.f;
#pragma unroll
    for (int p = 0; p < 8; p++) s += pctx[(size_t)p * (32 * ND) + i];
    ctx[i] = s;
}

extern "C" void kernel_launch(void* const* d_in, const int* in_sizes, int n_in,
                              void* d_out, int out_size, void* d_ws, size_t ws_size,
                              hipStream_t stream) {
    const float* query  = (const float*)d_in[0];
    const float* values = (const float*)d_in[1];
    const float* W1     = (const float*)d_in[2];
    const float* b1     = (const float*)d_in[3];
    const float* W2     = (const float*)d_in[4];
    const float* b2     = (const float*)d_in[5];
    const float* V      = (const float*)d_in[6];
    // d_in[7] = bv: uniform shift over softmax axis -> no effect on outputs. Dropped.

    float* ctx_out  = (float*)d_out;               // [32,512]
    float* attn_out = (float*)d_out + NB * ND;     // [32,4096]

    char* ws = (char*)d_ws;
    float*          qb     = (float*)ws;                                   // 64 KB
    unsigned short* W2Tt   = (unsigned short*)(ws + (64 << 10));           // 512 KB
    float*          scores = (float*)(ws + (64 << 10) + (512 << 10));      // 512 KB
    float*          pctx   = (float*)(ws + (64 << 10) + (1024 << 10));     // 512 KB

    hipMemsetAsync(scores, 0, (size_t)NB * NS * sizeof(float), stream);

    qproj_kernel<<<NB, 256, 0, stream>>>(query, W1, b1, b2, qb);
    w2t_kernel<<<128, 256, 0, stream>>>(W2, W2Tt);
    scores_kernel<<<dim3(2, 32, 32), 256, 0, stream>>>(values, W2Tt, qb, V, scores);
    softmax_kernel<<<NB, 256, 0, stream>>>(scores, attn_out);
    context_partial_kernel<<<dim3(8, 32), 256, 0, stream>>>(values, attn_out, pctx);
    context_reduce_kernel<<<64, 256, 0, stream>>>(pctx, ctx_out);
}

// Round 3
// 498.345 us; speedup vs baseline: 1.1193x; 1.0736x over previous
//
#include <hip/hip_runtime.h>
#include <hip/hip_bf16.h>
#include <stdint.h>

#define NB 32
#define NS 4096
#define ND 512

typedef __attribute__((ext_vector_type(8))) short short8;
typedef __attribute__((ext_vector_type(4))) float floatx4;

__device__ __forceinline__ short f2bf(float f) {
    unsigned int u = __builtin_bit_cast(unsigned int, f);
    return (short)((u + 0x8000u) >> 16);
}

__device__ __forceinline__ float fast_tanh(float x) {
    float e = __expf(2.0f * x);
    return 1.0f - 2.0f * __builtin_amdgcn_rcpf(e + 1.0f);
}

// K1a: qb[b][e] = sum_k query[b][k] * W1[k][e] + b1[e] + b2[e]
// grid (32 b, 8 e-slices); 256 threads = 64 cols x 4 k-slices of 128
__global__ void __launch_bounds__(256) qproj_kernel(
    const float* __restrict__ query, const float* __restrict__ W1,
    const float* __restrict__ b1, const float* __restrict__ b2,
    float* __restrict__ qb) {
    const int b  = blockIdx.x;
    const int es = blockIdx.y;
    const int t  = threadIdx.x;
    const int col = t & 63, kc = t >> 6;
    __shared__ float q[ND];
    __shared__ float red[256];
    q[t] = query[b * ND + t];
    q[t + 256] = query[b * ND + t + 256];
    __syncthreads();
    float acc = 0.f;
    const float* wp = W1 + (size_t)(kc * 128) * ND + es * 64 + col;
    const float* qp = q + kc * 128;
#pragma unroll 8
    for (int k = 0; k < 128; k++)
        acc += qp[k] * wp[(size_t)k * ND];
    red[t] = acc;
    __syncthreads();
    if (t < 64) {
        float s = red[t] + red[t + 64] + red[t + 128] + red[t + 192];
        int e = es * 64 + t;
        qb[b * ND + e] = s + b1[e] + b2[e];
    }
}

// K1b: shuffle W2 (fp32 [k][e]) into bf16 tiled layout for global_load_lds:
// chunk g = (nt: g>>14, ks: (g>>10)&15, kq: (g>>8)&3, n: g&255);
// holds bf16(W2[ks*32+kq*8+j][nt*256+n]) for j=0..7 at W2Tt + g*8.
__global__ void __launch_bounds__(256) w2t_kernel(
    const float* __restrict__ W2, unsigned short* __restrict__ W2Tt) {
    int g = blockIdx.x * 256 + threadIdx.x;   // 32768 chunks
    int nt = g >> 14;
    int ks = (g >> 10) & 15;
    int kq = (g >> 8) & 3;
    int n  = g & 255;
    int e  = nt * 256 + n;
    int k0 = ks * 32 + kq * 8;
    short8 v;
#pragma unroll
    for (int j = 0; j < 8; j++)
        v[j] = f2bf(W2[(size_t)(k0 + j) * ND + e]);
    *(short8*)&W2Tt[(size_t)g * 8] = v;
}

// K2: scores[b][s] += sum_{e in 256-wide ntile} tanh((values[b] @ W2)[s][e] + qb[b][e]) * V[e]
// Tile: 64 s-rows x 256 n-cols, K=512 in 16 steps of 32. 4 waves, each 64x64 (acc 4x4).
// A staged as raw fp32 via global_load_lds with XOR chunk swizzle; bf16 cvt at frag read.
// B staged bf16 via global_load_lds from pre-shuffled W2Tt. Double-buffered, 1 barrier/step.
// LDS 50KB -> 3 blocks/CU (launch_bounds(256,3) caps VGPR at 170).
__global__ void __launch_bounds__(256, 3) scores_kernel(
    const float* __restrict__ values, const unsigned short* __restrict__ W2Tt,
    const float* __restrict__ qb, const float* __restrict__ V,
    float* __restrict__ scores) {
    const int nt = blockIdx.x;   // 0..1
    const int st = blockIdx.y;   // 0..63
    const int b  = blockIdx.z;   // 0..31
    const int n0 = nt * 256, s0 = st * 64;

    __shared__ __align__(16) float sA[2][2048];            // 2 x 8 KB fp32 (64 rows x 32 k)
    __shared__ __align__(16) unsigned short sB[2][8192];   // 2 x 16 KB bf16 (256 n x 32 k)
    __shared__ float sQb[256];
    __shared__ float sV[256];

    const int tid  = threadIdx.x;
    const int lane = tid & 63;
    const int wave = tid >> 6;          // 0..3 -> n-col offset wave*64
    const int mr = lane & 15;
    const int q  = lane >> 4;

    sQb[tid] = qb[b * ND + n0 + tid];
    sV[tid]  = V[n0 + tid];

    floatx4 acc[4][4] = {};

    const float* abase = values + ((size_t)b * NS + s0) * ND;
    const unsigned short* bbase = W2Tt + (size_t)(nt * 16) * 8192;

    // ---- prologue: stage k-step 0 into buffer 0 ----
#pragma unroll
    for (int r = 0; r < 4; r++) {
        int c = tid + 256 * r;
        __builtin_amdgcn_global_load_lds(
            (const __attribute__((address_space(1))) unsigned int*)(bbase + c * 8),
            (__attribute__((address_space(3))) unsigned int*)&sB[0][c * 8],
            16, 0, 0);
    }
#pragma unroll
    for (int r = 0; r < 2; r++) {
        int c = tid + 256 * r;
        int row = c >> 3;
        int kq4 = (c & 7) ^ (row & 7);          // bank swizzle (within-row chunk perm)
        __builtin_amdgcn_global_load_lds(
            (const __attribute__((address_space(1))) unsigned int*)(abase + (size_t)row * ND + kq4 * 4),
            (__attribute__((address_space(3))) unsigned int*)&sA[0][c * 4],
            16, 0, 0);
    }
    __syncthreads();

    for (int ks = 0; ks < 16; ks++) {
        const int cur = ks & 1, nxt = cur ^ 1;

        // ---- read fragments of [cur] FIRST (no new vm ops since barrier) ----
        short8 af[4], bfr[4];
#pragma unroll
        for (int i = 0; i < 4; i++) {
            int row = i * 16 + mr;
            int c0 = row * 8 + ((2 * q) ^ (mr & 7));
            float4 f0 = *(const float4*)&sA[cur][c0 * 4];
            float4 f1 = *(const float4*)&sA[cur][(c0 ^ 1) * 4];
            short8 a;
            a[0] = f2bf(f0.x); a[1] = f2bf(f0.y); a[2] = f2bf(f0.z); a[3] = f2bf(f0.w);
            a[4] = f2bf(f1.x); a[5] = f2bf(f1.y); a[6] = f2bf(f1.z); a[7] = f2bf(f1.w);
            af[i] = a;
        }
#pragma unroll
        for (int j = 0; j < 4; j++)
            bfr[j] = *(const short8*)&sB[cur][(q * 256 + wave * 64 + j * 16 + mr) * 8];

        // ---- prefetch [ks+1] into [nxt]; drain happens at the barrier, covered by MFMA ----
        if (ks < 15) {
            const unsigned short* bsrc = bbase + (size_t)(ks + 1) * 8192;
            const float* asrc = abase + (ks + 1) * 32;
#pragma unroll
            for (int r = 0; r < 4; r++) {
                int c = tid + 256 * r;
                __builtin_amdgcn_global_load_lds(
                    (const __attribute__((address_space(1))) unsigned int*)(bsrc + c * 8),
                    (__attribute__((address_space(3))) unsigned int*)&sB[nxt][c * 8],
                    16, 0, 0);
            }
#pragma unroll
            for (int r = 0; r < 2; r++) {
                int c = tid + 256 * r;
                int row = c >> 3;
                int kq4 = (c & 7) ^ (row & 7);
                __builtin_amdgcn_global_load_lds(
                    (const __attribute__((address_space(1))) unsigned int*)(asrc + (size_t)row * ND + kq4 * 4),
                    (__attribute__((address_space(3))) unsigned int*)&sA[nxt][c * 4],
                    16, 0, 0);
            }
        }

#pragma unroll
        for (int i = 0; i < 4; i++)
#pragma unroll
            for (int j = 0; j < 4; j++)
                acc[i][j] = __builtin_amdgcn_mfma_f32_16x16x32_bf16(af[i], bfr[j], acc[i][j], 0, 0, 0);

        __syncthreads();
    }

    // ---- epilogue: tanh(P + qb) * V, reduce over cols, atomic partial scores ----
    float vcoef[4], qadd[4];
#pragma unroll
    for (int j = 0; j < 4; j++) {
        int col = wave * 64 + j * 16 + mr;
        vcoef[j] = sV[col];
        qadd[j]  = sQb[col];
    }

#pragma unroll
    for (int i = 0; i < 4; i++) {
#pragma unroll
        for (int r = 0; r < 4; r++) {
            float p = 0.f;
#pragma unroll
            for (int j = 0; j < 4; j++)
                p += fast_tanh(acc[i][j][r] + qadd[j]) * vcoef[j];
            p += __shfl_xor(p, 1);
            p += __shfl_xor(p, 2);
            p += __shfl_xor(p, 4);
            p += __shfl_xor(p, 8);
            if (mr == 0) {
                int row = i * 16 + q * 4 + r;
                atomicAdd(&scores[(size_t)b * NS + s0 + row], p);
            }
        }
    }
}

// K3: softmax over S per batch
__global__ void __launch_bounds__(256) softmax_kernel(
    const float* __restrict__ scores, float* __restrict__ attn) {
    int b = blockIdx.x;
    int t = threadIdx.x;
    __shared__ float red[4];
    __shared__ float bcast[2];
    const float* sc = scores + (size_t)b * NS;
    float v[16];
    float m = -1e30f;
#pragma unroll
    for (int i = 0; i < 16; i++) { v[i] = sc[t + i * 256]; m = fmaxf(m, v[i]); }
    for (int o = 32; o; o >>= 1) m = fmaxf(m, __shfl_xor(m, o));
    if ((t & 63) == 0) red[t >> 6] = m;
    __syncthreads();
    if (t == 0) bcast[0] = fmaxf(fmaxf(red[0], red[1]), fmaxf(red[2], red[3]));
    __syncthreads();
    m = bcast[0];
    float sum = 0.f;
#pragma unroll
    for (int i = 0; i < 16; i++) { v[i] = __expf(v[i] - m); sum += v[i]; }
    for (int o = 32; o; o >>= 1) sum += __shfl_xor(sum, o);
    if ((t & 63) == 0) red[t >> 6] = sum;
    __syncthreads();
    if (t == 0) bcast[1] = red[0] + red[1] + red[2] + red[3];
    __syncthreads();
    float inv = 1.0f / bcast[1];
    float* ao = attn + (size_t)b * NS;
#pragma unroll
    for (int i = 0; i < 16; i++) ao[t + i * 256] = v[i] * inv;
}

// K4a: pctx[sc][b][d] = sum_{s in chunk} attn[b][s] * values[b][s][d]  (no atomics)
__global__ void __launch_bounds__(256) context_partial_kernel(
    const float* __restrict__ values, const float* __restrict__ attn,
    float* __restrict__ pctx) {
    int sc = blockIdx.x;  // 0..7 (512 s each)
    int b  = blockIdx.y;  // 0..31
    int t  = threadIdx.x;
    __shared__ float sAttn[512];
    sAttn[t]       = attn[(size_t)b * NS + sc * 512 + t];
    sAttn[t + 256] = attn[(size_t)b * NS + sc * 512 + t + 256];
    __syncthreads();
    int d = t * 2;
    const float2* vp = (const float2*)(values + ((size_t)b * NS + sc * 512) * ND + d);
    float ax = 0.f, ay = 0.f;
#pragma unroll 8
    for (int s = 0; s < 512; s++) {
        float a = sAttn[s];
        float2 v = vp[(size_t)s * 256];
        ax += a * v.x; ay += a * v.y;
    }
    pctx[((size_t)sc * 32 + b) * ND + d]     = ax;
    pctx[((size_t)sc * 32 + b) * ND + d + 1] = ay;
}

// K4b: ctx[b][d] = sum_sc pctx[sc][b][d]
__global__ void __launch_bounds__(256) context_reduce_kernel(
    const float* __restrict__ pctx, float* __restrict__ ctx) {
    int i = blockIdx.x * 256 + threadIdx.x;  // 16384
    float s = 0.f;
#pragma unroll
    for (int p = 0; p < 8; p++) s += pctx[(size_t)p * (32 * ND) + i];
    ctx[i] = s;
}

extern "C" void kernel_launch(void* const* d_in, const int* in_sizes, int n_in,
                              void* d_out, int out_size, void* d_ws, size_t ws_size,
                              hipStream_t stream) {
    const float* query  = (const float*)d_in[0];
    const float* values = (const float*)d_in[1];
    const float* W1     = (const float*)d_in[2];
    const float* b1     = (const float*)d_in[3];
    const float* W2     = (const float*)d_in[4];
    const float* b2     = (const float*)d_in[5];
    const float* V      = (const float*)d_in[6];
    // d_in[7] = bv: uniform shift over softmax axis -> no effect on outputs. Dropped.

    float* ctx_out  = (float*)d_out;               // [32,512]
    float* attn_out = (float*)d_out + NB * ND;     // [32,4096]

    char* ws = (char*)d_ws;
    float*          qb     = (float*)ws;                                   // 64 KB
    unsigned short* W2Tt   = (unsigned short*)(ws + (64 << 10));           // 512 KB
    float*          scores = (float*)(ws + (64 << 10) + (512 << 10));      // 512 KB
    float*          pctx   = (float*)(ws + (64 << 10) + (1024 << 10));     // 512 KB

    hipMemsetAsync(scores, 0, (size_t)NB * NS * sizeof(float), stream);

    qproj_kernel<<<dim3(NB, 8), 256, 0, stream>>>(query, W1, b1, b2, qb);
    w2t_kernel<<<128, 256, 0, stream>>>(W2, W2Tt);
    scores_kernel<<<dim3(2, 64, 32), 256, 0, stream>>>(values, W2Tt, qb, V, scores);
    softmax_kernel<<<NB, 256, 0, stream>>>(scores, attn_out);
    context_partial_kernel<<<dim3(8, 32), 256, 0, stream>>>(values, attn_out, pctx);
    context_reduce_kernel<<<64, 256, 0, stream>>>(pctx, ctx_out);
}